// Round 3
// baseline (953.836 us; speedup 1.0000x reference)
//
#include <hip/hip_runtime.h>
#include <hip/hip_bf16.h>

typedef __attribute__((ext_vector_type(8))) short short8;
typedef __attribute__((ext_vector_type(4))) float floatx4;
typedef __attribute__((ext_vector_type(4))) int int4v;

#define EDIM 256
#define HDIM 512
#define LDIM 16
#define NCHAIN 4096

__device__ __forceinline__ float fsigmoid(float x) {
    return 1.0f / (1.0f + __expf(-x));
}
__device__ __forceinline__ float ftanh(float x) {
    return 2.0f / (1.0f + __expf(-2.0f * x)) - 1.0f;
}

// ---------------------------------------------------------------------------
// Prepass: detect float dtype (fp32 vs bf16) on-device, emit bf16 weights +
// combined fp32 bias into workspace.
// ---------------------------------------------------------------------------
__global__ void prep(const void* __restrict__ embp, const void* __restrict__ wihp,
                     const void* __restrict__ whhp, const void* __restrict__ bihp,
                     const void* __restrict__ bhhp,
                     short* __restrict__ emb_o, short* __restrict__ wih_o,
                     short* __restrict__ whh_o, float* __restrict__ bias_o)
{
    const short* det = (const short*)wihp;
    bool is_bf16 = true;
    for (int i = 0; i < 64; i += 2) {
        int e = (((unsigned short)det[i]) >> 7) & 0xFF;
        if (e > 0x7B) is_bf16 = false;
    }

    const int tid = blockIdx.x * blockDim.x + threadIdx.x;
    const int stride = gridDim.x * blockDim.x;

    if (is_bf16) {
        const short* e = (const short*)embp;
        const short* wi = (const short*)wihp;
        const short* wh = (const short*)whhp;
        const __hip_bfloat16* bi = (const __hip_bfloat16*)bihp;
        const __hip_bfloat16* bh = (const __hip_bfloat16*)bhhp;
        for (int i = tid; i < EDIM * 256; i += stride) emb_o[i] = e[i];
        for (int i = tid; i < 4 * HDIM * EDIM; i += stride) wih_o[i] = wi[i];
        for (int i = tid; i < 4 * HDIM * HDIM; i += stride) whh_o[i] = wh[i];
        for (int i = tid; i < 4 * HDIM; i += stride)
            bias_o[i] = __bfloat162float(bi[i]) + __bfloat162float(bh[i]);
    } else {
        const float* e = (const float*)embp;
        const float* wi = (const float*)wihp;
        const float* wh = (const float*)whhp;
        const float* bi = (const float*)bihp;
        const float* bh = (const float*)bhhp;
        for (int i = tid; i < EDIM * 256; i += stride)
            ((__hip_bfloat16*)emb_o)[i] = __float2bfloat16(e[i]);
        for (int i = tid; i < 4 * HDIM * EDIM; i += stride)
            ((__hip_bfloat16*)wih_o)[i] = __float2bfloat16(wi[i]);
        for (int i = tid; i < 4 * HDIM * HDIM; i += stride)
            ((__hip_bfloat16*)whh_o)[i] = __float2bfloat16(wh[i]);
        for (int i = tid; i < 4 * HDIM; i += stride) bias_o[i] = bi[i] + bh[i];
    }
}

// ---------------------------------------------------------------------------
// grid: (4 j-tiles, 64 chain-tiles); block: 512 threads = 8 waves.
// wave w owns hidden units j = jt*128 + w*16 .. +15, all 4 gates, 64 chains.
// cio = d_out (fp32): holds c-state for t<15; at t==15 receives final h.
// ---------------------------------------------------------------------------
__launch_bounds__(512, 2)
__global__ void lstm_step(const int* __restrict__ seq,     // [4096,16] char ids
                          const int* __restrict__ lens,    // [4096]
                          const short* __restrict__ emb,   // [256,256] bf16
                          const short* __restrict__ wih,   // [2048,256] bf16
                          const short* __restrict__ whh,   // [2048,512] bf16
                          const float* __restrict__ bias,  // [2048] fp32
                          const short* __restrict__ hread, // [4096,512] bf16
                          short* __restrict__ hwrite,      // [4096,512] bf16
                          float* __restrict__ cio,         // [4096,512] fp32
                          int t)
{
    const int jt = blockIdx.x;          // 0..3
    const int mt = blockIdx.y;          // 0..63
    const int wave = threadIdx.x >> 6;  // 0..7
    const int lane = threadIdx.x & 63;
    const int q = lane >> 4;            // quad 0..3
    const int ln = lane & 15;

    const int jglob = jt * 128 + wave * 16 + ln;  // hidden unit 0..511
    const int chain_base = mt * 64;

    // char ids for A-fragment rows (A row m = lane&15)
    int ids[4];
#pragma unroll
    for (int mf = 0; mf < 4; ++mf) {
        int chain = chain_base + mf * 16 + ln;
        ids[mf] = seq[chain * LDIM + t];
    }

    int wrow[4];
#pragma unroll
    for (int g = 0; g < 4; ++g) wrow[g] = g * HDIM + jglob;

    floatx4 acc[4][4];  // [gate][mfrag]
#pragma unroll
    for (int g = 0; g < 4; ++g)
#pragma unroll
        for (int mf = 0; mf < 4; ++mf)
            acc[g][mf] = (floatx4){0.f, 0.f, 0.f, 0.f};

    // ---- phase 1: x @ W_ih^T  (K = 256) ----
#pragma unroll
    for (int kc = 0; kc < 8; ++kc) {
        const int k0 = kc * 32 + q * 8;
        short8 b[4];
#pragma unroll
        for (int g = 0; g < 4; ++g)
            b[g] = *(const short8*)(wih + wrow[g] * EDIM + k0);
#pragma unroll
        for (int mf = 0; mf < 4; ++mf) {
            short8 a = *(const short8*)(emb + ids[mf] * EDIM + k0);
#pragma unroll
            for (int g = 0; g < 4; ++g)
                acc[g][mf] = __builtin_amdgcn_mfma_f32_16x16x32_bf16(
                    a, b[g], acc[g][mf], 0, 0, 0);
        }
    }

    // ---- phase 2: h @ W_hh^T  (K = 512), h==0 at t==0 so skip ----
    if (t > 0) {
#pragma unroll
        for (int kc = 0; kc < 16; ++kc) {
            const int k0 = kc * 32 + q * 8;
            short8 b[4];
#pragma unroll
            for (int g = 0; g < 4; ++g)
                b[g] = *(const short8*)(whh + wrow[g] * HDIM + k0);
#pragma unroll
            for (int mf = 0; mf < 4; ++mf) {
                int chain = chain_base + mf * 16 + ln;
                short8 a = *(const short8*)(hread + chain * HDIM + k0);
#pragma unroll
                for (int g = 0; g < 4; ++g)
                    acc[g][mf] = __builtin_amdgcn_mfma_f32_16x16x32_bf16(
                        a, b[g], acc[g][mf], 0, 0, 0);
            }
        }
    }

    float bs[4];
#pragma unroll
    for (int g = 0; g < 4; ++g) bs[g] = bias[wrow[g]];

    // ---- epilogue: LSTM cell update. C/D: col=lane&15, row=q*4+reg ----
#pragma unroll
    for (int mf = 0; mf < 4; ++mf) {
        int4v len4 = *(const int4v*)(lens + chain_base + mf * 16 + q * 4);
#pragma unroll
        for (int r = 0; r < 4; ++r) {
            int chain = chain_base + mf * 16 + q * 4 + r;
            int off = chain * HDIM + jglob;
            float pi = acc[0][mf][r] + bs[0];
            float pf = acc[1][mf][r] + bs[1];
            float pg = acc[2][mf][r] + bs[2];
            float po = acc[3][mf][r] + bs[3];
            float ig = fsigmoid(pi);
            float fg = fsigmoid(pf);
            float gg = ftanh(pg);
            float og = fsigmoid(po);
            float c_old = (t > 0) ? cio[off] : 0.0f;
            float c_new = fg * c_old + ig * gg;
            float h_new = og * ftanh(c_new);
            float h_old = (t > 0)
                ? __bfloat162float(((const __hip_bfloat16*)hread)[off]) : 0.0f;
            bool msk = len4[r] > t;
            float h_st = msk ? h_new : h_old;
            float c_st = msk ? c_new : c_old;
            ((__hip_bfloat16*)hwrite)[off] = __float2bfloat16(h_st);
            // d_out carries c for t<15; at the last step it receives final h (fp32)
            cio[off] = (t == LDIM - 1) ? h_st : c_st;
        }
    }
}

extern "C" void kernel_launch(void* const* d_in, const int* in_sizes, int n_in,
                              void* d_out, int out_size, void* d_ws, size_t ws_size,
                              hipStream_t stream) {
    const int* seq  = (const int*)d_in[0];
    const int* lens = (const int*)d_in[1];

    // workspace layout (bytes):
    //   [0, 4M)    h_even  bf16 [4096][512]
    //   [4M, 8M)   h_odd   bf16 [4096][512]
    //   [8M, ...)  emb_bf 128K | wih_bf 1M | whh_bf 2M | bias 8K   (~11.14 MB total)
    char* w = (char*)d_ws;
    short* h_even = (short*)w;
    short* h_odd  = (short*)(w + 4u * 1024 * 1024);
    short* emb_bf = (short*)(w + 8u * 1024 * 1024);
    short* wih_bf = emb_bf + EDIM * 256;
    short* whh_bf = wih_bf + 4 * HDIM * EDIM;
    float* bias   = (float*)(whh_bf + 4 * HDIM * HDIM);
    float* cio    = (float*)d_out;   // fp32: c-state scratch, then final h

    prep<<<256, 256, 0, stream>>>(d_in[2], d_in[3], d_in[4], d_in[5], d_in[6],
                                  emb_bf, wih_bf, whh_bf, bias);

    dim3 grid(4, 64);
    dim3 block(512);
    for (int t = 0; t < 16; ++t) {
        short* hw       = (t & 1) ? h_odd  : h_even;
        const short* hr = (t & 1) ? h_even : h_odd;  // buffer written at t-1
        lstm_step<<<grid, block, 0, stream>>>(seq, lens, emb_bf, wih_bf, whh_bf,
                                              bias, hr, hw, cio, t);
    }
}

// Round 4
// 465.605 us; speedup vs baseline: 2.0486x; 2.0486x over previous
//
#include <hip/hip_runtime.h>
#include <hip/hip_bf16.h>

typedef __attribute__((ext_vector_type(8))) short short8;
typedef __attribute__((ext_vector_type(4))) float floatx4;

#define EDIM 256
#define HDIM 512
#define LDIM 16
#define NCHAIN 4096
#define NCOL 2048

#define BM 256      // chains per block
#define KC 32       // k-chunk
#define LDA 40      // padded LDS row (elems) for A (32 + 8)
#define LDB 40      // padded LDS row for B

__device__ __forceinline__ float fsigmoid(float x){ return 1.0f/(1.0f+__expf(-x)); }
__device__ __forceinline__ float ftanh(float x){ return 2.0f/(1.0f+__expf(-2.0f*x))-1.0f; }

__device__ __forceinline__ bool detect_bf16(const short* p) {
    // fp32 buffers' even shorts are low mantissa bits (~uniform) -> exponent
    // field frequently > 0x7B; true bf16 U(-.05,.05) weights never exceed it.
    bool bf = true;
    for (int i = 0; i < 64; i += 2) {
        int e = (((unsigned short)p[i]) >> 7) & 0xFF;
        if (e > 0x7B) bf = false;
    }
    return bf;
}

// ---------------------------------------------------------------------------
// W_hh -> bf16 (copy if already bf16)
// ---------------------------------------------------------------------------
__global__ void conv_whh(const void* __restrict__ whhp, short* __restrict__ whh_o) {
    bool bf = detect_bf16((const short*)whhp);
    int tid = blockIdx.x * blockDim.x + threadIdx.x;
    int stride = gridDim.x * blockDim.x;
    if (bf) {
        const short* s = (const short*)whhp;
        for (int i = tid; i < NCOL * HDIM; i += stride) whh_o[i] = s[i];
    } else {
        const float* s = (const float*)whhp;
        for (int i = tid; i < NCOL * HDIM; i += stride)
            ((__hip_bfloat16*)whh_o)[i] = __float2bfloat16(s[i]);
    }
}

// ---------------------------------------------------------------------------
// xg[id][col] = emb[id] . W_ih[col] + b_ih[col] + b_hh[col]   (bf16 out)
// grid (16 id-tiles, 64 col-tiles), 256 threads. Only 256 distinct x rows!
// ---------------------------------------------------------------------------
__global__ void build_xg(const void* __restrict__ embp, const void* __restrict__ wihp,
                         const void* __restrict__ bihp, const void* __restrict__ bhhp,
                         short* __restrict__ xg)
{
    __shared__ float es[16][EDIM];        // 16 KB
    __shared__ float wsm[32][EDIM + 1];   // 32.1 KB (pad breaks bank conflicts)
    bool bf = detect_bf16((const short*)wihp);
    const int idt = blockIdx.x, ct = blockIdx.y, tt = threadIdx.x;

    if (bf) {
        const __hip_bfloat16* e = (const __hip_bfloat16*)embp;
        const __hip_bfloat16* wv = (const __hip_bfloat16*)wihp;
        for (int p = 0; p < 16; ++p) es[p][tt] = __bfloat162float(e[(idt*16+p)*EDIM + tt]);
        for (int p = 0; p < 32; ++p) wsm[p][tt] = __bfloat162float(wv[(ct*32+p)*EDIM + tt]);
    } else {
        const float* e = (const float*)embp;
        const float* wv = (const float*)wihp;
        for (int p = 0; p < 16; ++p) es[p][tt] = e[(idt*16+p)*EDIM + tt];
        for (int p = 0; p < 32; ++p) wsm[p][tt] = wv[(ct*32+p)*EDIM + tt];
    }
    __syncthreads();

    const int col_l = tt & 31, grp = tt >> 5;   // 8 groups x 2 ids
    const int col = ct * 32 + col_l;
    float bsum = bf ? (__bfloat162float(((const __hip_bfloat16*)bihp)[col]) +
                       __bfloat162float(((const __hip_bfloat16*)bhhp)[col]))
                    : (((const float*)bihp)[col] + ((const float*)bhhp)[col]);
    float a0 = 0.f, a1 = 0.f;
    for (int k = 0; k < EDIM; ++k) {
        float wv = wsm[col_l][k];
        a0 += es[grp*2+0][k] * wv;
        a1 += es[grp*2+1][k] * wv;
    }
    ((__hip_bfloat16*)xg)[(idt*16 + grp*2 + 0)*NCOL + col] = __float2bfloat16(a0 + bsum);
    ((__hip_bfloat16*)xg)[(idt*16 + grp*2 + 1)*NCOL + col] = __float2bfloat16(a1 + bsum);
}

// ---------------------------------------------------------------------------
// One LSTM time step: gates = xg[id] + h_prev @ W_hh^T  (K=512 via LDS tiles)
// grid (16 mt, 16 jt); block 512 thr = 8 waves (4 m-subs x 2 n-subs).
// Wave tile 64 chains x (16 j x 4 gates); cell update fully in-lane.
// cio = d_out fp32: c-state for t<15; final h at t==15.
// ---------------------------------------------------------------------------
__launch_bounds__(512, 2)
__global__ void lstm_step(const int* __restrict__ seq, const int* __restrict__ lens,
                          const short* __restrict__ whh,   // bf16 [2048][512]
                          const short* __restrict__ xg,    // bf16 [256][2048]
                          const short* __restrict__ hread, // bf16 [4096][512]
                          short* __restrict__ hwrite,      // bf16 [4096][512]
                          float* __restrict__ cio,         // fp32 [4096][512]
                          int t)
{
    __shared__ short Asm[2][BM * LDA];    // 40 KB
    __shared__ short Bsm[2][128 * LDB];   // 20 KB

    const int mt = blockIdx.x, jt = blockIdx.y;
    const int tid = threadIdx.x;
    const int wave = tid >> 6, lane = tid & 63;
    const int q = lane >> 4, ln = lane & 15;
    const int ms = wave & 3, ns = wave >> 2;
    const int jloc = ns * 16 + ln;        // 0..31 within block's j-slab
    const int j = jt * 32 + jloc;         // global hidden unit

    // ids + lens for the 16 (mf,r) epilogue rows (issued early, used late)
    int ids[16], lns[16];
#pragma unroll
    for (int mf = 0; mf < 4; ++mf)
#pragma unroll
        for (int r = 0; r < 4; ++r) {
            int chain = mt * BM + ms * 64 + mf * 16 + q * 4 + r;
            ids[mf * 4 + r] = seq[chain * LDIM + t];
            lns[mf * 4 + r] = lens[chain];
        }

    floatx4 acc[4][4];  // [gate][mfrag]
#pragma unroll
    for (int g = 0; g < 4; ++g)
#pragma unroll
        for (int mf = 0; mf < 4; ++mf) acc[g][mf] = (floatx4){0.f, 0.f, 0.f, 0.f};

    if (t > 0) {
        // stage chunk 0 into buffer 0
        {
#pragma unroll
            for (int p = 0; p < 2; ++p) {
                int task = p * 512 + tid;
                int row = task >> 2, seg = task & 3;
                short8 v = *(const short8*)(hread + (mt*BM + row)*HDIM + seg*8);
                *(short8*)&Asm[0][row*LDA + seg*8] = v;
            }
            {
                int row = tid >> 2, seg = tid & 3;
                int gcol = (row >> 5) * HDIM + jt * 32 + (row & 31);
                short8 v = *(const short8*)(whh + gcol*HDIM + seg*8);
                *(short8*)&Bsm[0][row*LDB + seg*8] = v;
            }
        }
        __syncthreads();

        for (int kc = 0; kc < 16; ++kc) {
            int b = kc & 1;
            if (kc < 15) {  // prefetch next chunk into other buffer
                int k0 = (kc + 1) * KC;
#pragma unroll
                for (int p = 0; p < 2; ++p) {
                    int task = p * 512 + tid;
                    int row = task >> 2, seg = task & 3;
                    short8 v = *(const short8*)(hread + (mt*BM + row)*HDIM + k0 + seg*8);
                    *(short8*)&Asm[b^1][row*LDA + seg*8] = v;
                }
                {
                    int row = tid >> 2, seg = tid & 3;
                    int gcol = (row >> 5) * HDIM + jt * 32 + (row & 31);
                    short8 v = *(const short8*)(whh + gcol*HDIM + k0 + seg*8);
                    *(short8*)&Bsm[b^1][row*LDB + seg*8] = v;
                }
            }
            // compute on buffer b
            short8 af[4], bfr[4];
#pragma unroll
            for (int mf = 0; mf < 4; ++mf)
                af[mf] = *(const short8*)&Asm[b][(ms*64 + mf*16 + ln)*LDA + q*8];
#pragma unroll
            for (int g = 0; g < 4; ++g)
                bfr[g] = *(const short8*)&Bsm[b][(g*32 + jloc)*LDB + q*8];
#pragma unroll
            for (int g = 0; g < 4; ++g)
#pragma unroll
                for (int mf = 0; mf < 4; ++mf)
                    acc[g][mf] = __builtin_amdgcn_mfma_f32_16x16x32_bf16(
                        af[mf], bfr[g], acc[g][mf], 0, 0, 0);
            __syncthreads();
        }
    }

    // ---- epilogue: xg gather + cell update. C/D: col=lane&15, row=q*4+r ----
    const bool notlast = (t < LDIM - 1);
#pragma unroll
    for (int mf = 0; mf < 4; ++mf)
#pragma unroll
        for (int r = 0; r < 4; ++r) {
            int chain = mt*BM + ms*64 + mf*16 + q*4 + r;
            int off = chain * HDIM + j;
            int id = ids[mf*4 + r];
            float pre[4];
#pragma unroll
            for (int g = 0; g < 4; ++g)
                pre[g] = acc[g][mf][r] +
                    __bfloat162float(((const __hip_bfloat16*)xg)[id*NCOL + g*HDIM + j]);
            float ig = fsigmoid(pre[0]);
            float fg = fsigmoid(pre[1]);
            float gg = ftanh(pre[2]);
            float og = fsigmoid(pre[3]);
            float c_old = (t > 0) ? cio[off] : 0.f;
            float c_new = fg * c_old + ig * gg;
            float h_new = og * ftanh(c_new);
            float h_old = (t > 0) ? __bfloat162float(((const __hip_bfloat16*)hread)[off]) : 0.f;
            bool mk = lns[mf*4 + r] > t;
            float h_st = mk ? h_new : h_old;
            float c_st = mk ? c_new : c_old;
            if (notlast) {
                cio[off] = c_st;
                ((__hip_bfloat16*)hwrite)[off] = __float2bfloat16(h_st);
            } else {
                cio[off] = h_st;   // final output, fp32, in-place over c
            }
        }
}

extern "C" void kernel_launch(void* const* d_in, const int* in_sizes, int n_in,
                              void* d_out, int out_size, void* d_ws, size_t ws_size,
                              hipStream_t stream) {
    const int* seq  = (const int*)d_in[0];
    const int* lens = (const int*)d_in[1];

    // ws: h_even 4M | h_odd 4M | xg 1M | whh_bf 2M  = 11.0 MB (<= proven 11.14)
    char* w = (char*)d_ws;
    short* h_even = (short*)w;
    short* h_odd  = (short*)(w + 4u*1024*1024);
    short* xg     = (short*)(w + 8u*1024*1024);
    short* whh_bf = (short*)(w + 9u*1024*1024);
    float* cio = (float*)d_out;

    conv_whh<<<512, 256, 0, stream>>>(d_in[4], whh_bf);
    build_xg<<<dim3(16, 64), 256, 0, stream>>>(d_in[2], d_in[3], d_in[5], d_in[6], xg);

    for (int t = 0; t < 16; ++t) {
        short* hw       = (t & 1) ? h_odd  : h_even;
        const short* hr = (t & 1) ? h_even : h_odd;
        lstm_step<<<dim3(16, 16), 512, 0, stream>>>(seq, lens, whh_bf, xg,
                                                    hr, hw, cio, t);
    }
}